// Round 17
// baseline (408.159 us; speedup 1.0000x reference)
//
#include <hip/hip_runtime.h>
#include <math.h>

// ---------------------------------------------------------------------------
// MaskingDecoder bf16-MFMA v15: r16 (400us PASS) + 64-col GEMM variant for
// all N=512 GEMMs (wq, wo, ffn2): tile 128x64, grids 2x (wq/wo 1024 blocks,
// ffn2 256/chunk -> all CUs busy). kv-proj + FFN1 + attention unchanged.
// ---------------------------------------------------------------------------

typedef unsigned short u16;
typedef __attribute__((ext_vector_type(8))) short bf16x8;
typedef __attribute__((ext_vector_type(4))) float f32x4;

__device__ __forceinline__ u16 f2b(float x) {
    union { float f; unsigned u; } v; v.f = x;
    unsigned r = v.u + 0x7fffu + ((v.u >> 16) & 1u);
    return (u16)(r >> 16);
}
__device__ __forceinline__ float b2f(u16 h) {
    union { unsigned u; float f; } v; v.u = ((unsigned)h) << 16;
    return v.f;
}
__device__ __forceinline__ unsigned cvtpk(float lo, float hi) {
    unsigned r;
    asm("v_cvt_pk_bf16_f32 %0, %1, %2" : "=v"(r) : "v"(lo), "v"(hi));
    return r;
}
__device__ __forceinline__ f32x4 mfma32(bf16x8 a, bf16x8 b, f32x4 c) {
    return __builtin_amdgcn_mfma_f32_16x16x32_bf16(a, b, c, 0, 0, 0);
}
// async global->LDS, 16B per lane; LDS base wave-uniform, dest = base+lane*16
__device__ __forceinline__ void gl16(const u16* g, u16* l) {
    __builtin_amdgcn_global_load_lds((const __attribute__((address_space(1))) void*)g,
                                     (__attribute__((address_space(3))) void*)l,
                                     16, 0, 0);
}
// XCD-aware swizzle of the linear block id (bijective when nwg % 8 == 0)
__device__ __forceinline__ int xcd_swz(int lin, int nwg) {
    return ((nwg & 7) == 0) ? ((lin & 7) * (nwg >> 3) + (lin >> 3)) : lin;
}

// ---------------- f32 -> bf16 weight convert --------------------------------
__global__ __launch_bounds__(256) void k_cvt(const float* __restrict__ in,
                                             u16* __restrict__ out, const int n)
{
    const int i = (blockIdx.x * 256 + threadIdx.x) * 4;
    if (i >= n) return;
    const float4 v = *(const float4*)&in[i];
    ushort4 o;
    o.x = f2b(v.x); o.y = f2b(v.y); o.z = f2b(v.z); o.w = f2b(v.w);
    *(ushort4*)&out[i] = o;
}

// ---------------- rope table: 16 (cos,sin) pairs per row --------------------
__global__ void k_rope_tab16(const float* __restrict__ t, float* __restrict__ tab,
                             const int n)
{
    const int idx = blockIdx.x * 256 + threadIdx.x;
    if (idx >= n * 16) return;
    const int r = idx >> 4, i = idx & 15;
    const float b0 = (float)(1e-4 / 2.0627);
    const float a0 = (float)(2.0 * 3.14159265358979323846 / 1e-4);
    const float invf = a0 * (float)pow((double)b0, (double)i * (1.0 / 16.0));
    const float ang = t[r] * invf;
    float sn, cs;
    sincosf(ang, &sn, &cs);
    tab[((size_t)r << 5) + (i << 1)]     = cs;
    tab[((size_t)r << 5) + (i << 1) + 1] = sn;
}

// ---------------- qtok build + layernorm -> bf16 ----------------------------
__global__ __launch_bounds__(128) void k_qtok_ln(
    const int* __restrict__ qidx, const float* __restrict__ uemb,
    const float* __restrict__ vpb, const float* __restrict__ w,
    const float* __restrict__ bb, u16* __restrict__ qtok, u16* __restrict__ xn)
{
    const int r = blockIdx.x, tid = threadIdx.x, c0 = tid << 2;
    float4 x;
    if (c0 < 256) {
        x = *(const float4*)&vpb[c0];
    } else {
        const int u = qidx[r];
        x = *(const float4*)&uemb[(size_t)u * 256 + (c0 - 256)];
    }
    ushort4 qo;
    qo.x = f2b(x.x); qo.y = f2b(x.y); qo.z = f2b(x.z); qo.w = f2b(x.w);
    *(ushort4*)&qtok[(size_t)r * 512 + c0] = qo;
    float s  = x.x + x.y + x.z + x.w;
    float s2 = x.x * x.x + x.y * x.y + x.z * x.z + x.w * x.w;
#pragma unroll
    for (int o = 32; o > 0; o >>= 1) { s += __shfl_down(s, o); s2 += __shfl_down(s2, o); }
    __shared__ float buf[4];
    if ((tid & 63) == 0) { buf[(tid >> 6) << 1] = s; buf[((tid >> 6) << 1) + 1] = s2; }
    __syncthreads();
    s = buf[0] + buf[2]; s2 = buf[1] + buf[3];
    const float mu = s * (1.f / 512.f);
    const float rs = rsqrtf(s2 * (1.f / 512.f) - mu * mu + 1e-5f);
    const float4 w4 = *(const float4*)&w[c0];
    const float4 b4 = *(const float4*)&bb[c0];
    ushort4 yo;
    yo.x = f2b((x.x - mu) * rs * w4.x + b4.x);
    yo.y = f2b((x.y - mu) * rs * w4.y + b4.y);
    yo.z = f2b((x.z - mu) * rs * w4.z + b4.z);
    yo.w = f2b((x.w - mu) * rs * w4.w + b4.w);
    *(ushort4*)&xn[(size_t)r * 512 + c0] = yo;
}

// ---------------- layernorm f32-in -> bf16-out ------------------------------
__global__ __launch_bounds__(128) void k_ln_f(
    const float* __restrict__ in, const float* __restrict__ w,
    const float* __restrict__ bb, u16* __restrict__ outp)
{
    const int r = blockIdx.x, tid = threadIdx.x, c0 = tid << 2;
    const float4 x = *(const float4*)&in[(size_t)r * 512 + c0];
    float s  = x.x + x.y + x.z + x.w;
    float s2 = x.x * x.x + x.y * x.y + x.z * x.z + x.w * x.w;
#pragma unroll
    for (int o = 32; o > 0; o >>= 1) { s += __shfl_down(s, o); s2 += __shfl_down(s2, o); }
    __shared__ float buf[4];
    if ((tid & 63) == 0) { buf[(tid >> 6) << 1] = s; buf[((tid >> 6) << 1) + 1] = s2; }
    __syncthreads();
    s = buf[0] + buf[2]; s2 = buf[1] + buf[3];
    const float mu = s * (1.f / 512.f);
    const float rs = rsqrtf(s2 * (1.f / 512.f) - mu * mu + 1e-5f);
    const float4 w4 = *(const float4*)&w[c0];
    const float4 b4 = *(const float4*)&bb[c0];
    ushort4 yo;
    yo.x = f2b((x.x - mu) * rs * w4.x + b4.x);
    yo.y = f2b((x.y - mu) * rs * w4.y + b4.y);
    yo.z = f2b((x.z - mu) * rs * w4.z + b4.z);
    yo.w = f2b((x.w - mu) * rs * w4.w + b4.w);
    *(ushort4*)&outp[(size_t)r * 512 + c0] = yo;
}

// ---------------- layernorm bf16-in -> bf16-out -----------------------------
__global__ __launch_bounds__(128) void k_ln_h(
    const u16* __restrict__ in, const float* __restrict__ w,
    const float* __restrict__ bb, u16* __restrict__ outp)
{
    const int r = blockIdx.x, tid = threadIdx.x, c0 = tid << 2;
    const ushort4 xi = *(const ushort4*)&in[(size_t)r * 512 + c0];
    float4 x;
    x.x = b2f(xi.x); x.y = b2f(xi.y); x.z = b2f(xi.z); x.w = b2f(xi.w);
    float s  = x.x + x.y + x.z + x.w;
    float s2 = x.x * x.x + x.y * x.y + x.z * x.z + x.w * x.w;
#pragma unroll
    for (int o = 32; o > 0; o >>= 1) { s += __shfl_down(s, o); s2 += __shfl_down(s2, o); }
    __shared__ float buf[4];
    if ((tid & 63) == 0) { buf[(tid >> 6) << 1] = s; buf[((tid >> 6) << 1) + 1] = s2; }
    __syncthreads();
    s = buf[0] + buf[2]; s2 = buf[1] + buf[3];
    const float mu = s * (1.f / 512.f);
    const float rs = rsqrtf(s2 * (1.f / 512.f) - mu * mu + 1e-5f);
    const float4 w4 = *(const float4*)&w[c0];
    const float4 b4 = *(const float4*)&bb[c0];
    ushort4 yo;
    yo.x = f2b((x.x - mu) * rs * w4.x + b4.x);
    yo.y = f2b((x.y - mu) * rs * w4.y + b4.y);
    yo.z = f2b((x.z - mu) * rs * w4.z + b4.z);
    yo.w = f2b((x.w - mu) * rs * w4.w + b4.w);
    *(ushort4*)&outp[(size_t)r * 512 + c0] = yo;
}

// ---------------- MFMA GEMM 128x128 (kv projection, N=1024) -----------------
// EPI 1: rope(tab); c<512 -> out0 (k, pre-scaled by 1/8); c>=512 -> out1 (vT)
template <int EPI>
__global__ __launch_bounds__(256) void k_mgemm(
    const u16* __restrict__ A, const u16* __restrict__ W,
    const int N, const int K,
    u16* __restrict__ out0, u16* __restrict__ out1,
    const float* __restrict__ bias, const u16* __restrict__ res,
    const float* __restrict__ tab)
{
    __shared__ u16 Al[128 * 32];
    __shared__ u16 Bl[128 * 32];
    const int lin = blockIdx.x + gridDim.x * blockIdx.y;
    const int nwg = gridDim.x * gridDim.y;
    const int swz = xcd_swz(lin, nwg);
    const int bxx = swz % gridDim.x, byy = swz / gridDim.x;
    const int bm = byy << 7, bn = bxx << 7;
    const int tid = threadIdx.x;
    const int w = tid >> 6, l = tid & 63;
    const int wm = w >> 1, wn = w & 1;
    const int lr = l & 15, hi = l >> 4;
    const int srow = l >> 2, skq = (l & 3) << 3;
    const u16* Ap0 = A + (size_t)(bm + 16 * w + srow) * K + skq;
    const u16* Ap1 = A + (size_t)(bm + 64 + 16 * w + srow) * K + skq;
    const u16* Wp0 = W + (size_t)(bn + 16 * w + srow) * K + skq;
    const u16* Wp1 = W + (size_t)(bn + 64 + 16 * w + srow) * K + skq;
    u16* lA0 = Al + 512 * w;
    u16* lA1 = Al + 2048 + 512 * w;
    u16* lB0 = Bl + 512 * w;
    u16* lB1 = Bl + 2048 + 512 * w;
    f32x4 acc[4][4];
#pragma unroll
    for (int i = 0; i < 4; i++)
#pragma unroll
        for (int j = 0; j < 4; j++)
#pragma unroll
            for (int e = 0; e < 4; e++) acc[i][j][e] = 0.f;
    for (int k0 = 0; k0 < K; k0 += 32) {
        __syncthreads();
        gl16(Ap0 + k0, lA0);
        gl16(Ap1 + k0, lA1);
        gl16(Wp0 + k0, lB0);
        gl16(Wp1 + k0, lB1);
        __syncthreads();
        bf16x8 av[4], bv[4];
#pragma unroll
        for (int mi = 0; mi < 4; mi++)
            av[mi] = *(const bf16x8*)&Al[(wm * 64 + mi * 16 + lr) * 32 + hi * 8];
#pragma unroll
        for (int nj = 0; nj < 4; nj++)
            bv[nj] = *(const bf16x8*)&Bl[(wn * 64 + nj * 16 + lr) * 32 + hi * 8];
#pragma unroll
        for (int mi = 0; mi < 4; mi++)
#pragma unroll
            for (int nj = 0; nj < 4; nj++)
                acc[mi][nj] = mfma32(av[mi], bv[nj], acc[mi][nj]);
    }
#pragma unroll
    for (int mi = 0; mi < 4; mi++) {
#pragma unroll
        for (int nj = 0; nj < 4; nj++) {
            const int c = bn + wn * 64 + nj * 16 + lr;
#pragma unroll
            for (int j = 0; j < 4; j++) {
                const int r = bm + wm * 64 + mi * 16 + hi * 4 + j;
                const float x = acc[mi][nj][j];
                const float p = __shfl_xor(x, 1);
                const int ci = c & 63;
                float y = x;
                if (ci < 32) {
                    const int ii = ci >> 1;
                    const float cc = tab[((size_t)r << 5) + (ii << 1)];
                    const float ss = tab[((size_t)r << 5) + (ii << 1) + 1];
                    y = (c & 1) ? fmaf(x, cc, p * ss) : fmaf(x, cc, -p * ss);
                }
                if (c < 512) {
                    out0[(size_t)r * 512 + c] = f2b(y * 0.125f);  // fold DH^-0.5
                } else {
                    const int d = c - 512, hh = d >> 6, dd = d & 63;
                    const int bq = r >> 10, pos = r & 1023;
                    out1[(((size_t)(bq * 8 + hh)) * 64 + dd) * 1024 + pos] = f2b(y);
                }
            }
        }
    }
}

// ---------------- MFMA GEMM 128x64 (N=512: wq, wo, ffn2) --------------------
// tile 128 rows x 64 cols, 4 waves (2x2 of 64x32), 3x gl16/wave/K-step.
// EPI 0: rope(tab) -> out0 bf16
// EPI 2: out0 = acc + bias + res (bf16 residual add)
template <int EPI>
__global__ __launch_bounds__(256) void k_mgemm64(
    const u16* __restrict__ A, const u16* __restrict__ W,
    const int K,
    u16* __restrict__ out0, const float* __restrict__ bias,
    const u16* __restrict__ res, const float* __restrict__ tab)
{
    __shared__ u16 Al[128 * 32];
    __shared__ u16 Bl[64 * 32];
    const int lin = blockIdx.x + gridDim.x * blockIdx.y;
    const int nwg = gridDim.x * gridDim.y;
    const int swz = xcd_swz(lin, nwg);
    const int bxx = swz % gridDim.x, byy = swz / gridDim.x;
    const int bm = byy << 7, bn = bxx << 6;
    const int tid = threadIdx.x;
    const int w = tid >> 6, l = tid & 63;
    const int wm = w >> 1, wn = w & 1;
    const int lr = l & 15, hi = l >> 4;
    const int srow = l >> 2, skq = (l & 3) << 3;
    const u16* Ap0 = A + (size_t)(bm + 16 * w + srow) * K + skq;
    const u16* Ap1 = A + (size_t)(bm + 64 + 16 * w + srow) * K + skq;
    const u16* Wp0 = W + (size_t)(bn + 16 * w + srow) * K + skq;
    u16* lA0 = Al + 512 * w;
    u16* lA1 = Al + 2048 + 512 * w;
    u16* lB0 = Bl + 512 * w;
    f32x4 acc[4][2];
#pragma unroll
    for (int i = 0; i < 4; i++)
#pragma unroll
        for (int j = 0; j < 2; j++)
#pragma unroll
            for (int e = 0; e < 4; e++) acc[i][j][e] = 0.f;
    for (int k0 = 0; k0 < K; k0 += 32) {
        __syncthreads();
        gl16(Ap0 + k0, lA0);
        gl16(Ap1 + k0, lA1);
        gl16(Wp0 + k0, lB0);
        __syncthreads();
        bf16x8 av[4], bv[2];
#pragma unroll
        for (int mi = 0; mi < 4; mi++)
            av[mi] = *(const bf16x8*)&Al[(wm * 64 + mi * 16 + lr) * 32 + hi * 8];
#pragma unroll
        for (int nj = 0; nj < 2; nj++)
            bv[nj] = *(const bf16x8*)&Bl[(wn * 32 + nj * 16 + lr) * 32 + hi * 8];
#pragma unroll
        for (int mi = 0; mi < 4; mi++)
#pragma unroll
            for (int nj = 0; nj < 2; nj++)
                acc[mi][nj] = mfma32(av[mi], bv[nj], acc[mi][nj]);
    }
#pragma unroll
    for (int mi = 0; mi < 4; mi++) {
#pragma unroll
        for (int nj = 0; nj < 2; nj++) {
            const int c = bn + wn * 32 + nj * 16 + lr;
#pragma unroll
            for (int j = 0; j < 4; j++) {
                const int r = bm + wm * 64 + mi * 16 + hi * 4 + j;
                const float x = acc[mi][nj][j];
                if (EPI == 2) {
                    const float y = x + bias[c] + b2f(res[(size_t)r * 512 + c]);
                    out0[(size_t)r * 512 + c] = f2b(y);
                } else {
                    const float p = __shfl_xor(x, 1);
                    const int ci = c & 63;
                    float y = x;
                    if (ci < 32) {
                        const int ii = ci >> 1;
                        const float cc = tab[((size_t)r << 5) + (ii << 1)];
                        const float ss = tab[((size_t)r << 5) + (ii << 1) + 1];
                        y = (c & 1) ? fmaf(x, cc, p * ss) : fmaf(x, cc, -p * ss);
                    }
                    out0[(size_t)r * 512 + c] = f2b(y);
                }
            }
        }
    }
}

// ---------------- FFN1 (r12-proven): 128 rows x 64 ag-cols, XCD-swizzled ----
__global__ __launch_bounds__(256) void k_mffn1(
    const u16* __restrict__ A, const u16* __restrict__ W1,
    const float* __restrict__ b1, u16* __restrict__ ag)
{
    __shared__ u16 Al[128 * 32];
    __shared__ u16 Bl[128 * 32];
    const int lin = blockIdx.x + gridDim.x * blockIdx.y;
    const int nwg = gridDim.x * gridDim.y;
    const int swz = xcd_swz(lin, nwg);
    const int bxx = swz % gridDim.x, byy = swz / gridDim.x;
    const int bm = byy << 7, bn = bxx << 6;
    const int tid = threadIdx.x;
    const int w = tid >> 6, l = tid & 63;
    const int wm = w >> 1, wn = w & 1;
    const int lr = l & 15, hi = l >> 4;
    const int srow = l >> 2, skq = (l & 3) << 3;
    const u16* Ap0 = A  + (size_t)(bm + 16 * w + srow) * 512 + skq;
    const u16* Ap1 = A  + (size_t)(bm + 64 + 16 * w + srow) * 512 + skq;
    const u16* Wa  = W1 + (size_t)(bn + 16 * w + srow) * 512 + skq;
    const u16* Wg  = W1 + (size_t)(2048 + bn + 16 * w + srow) * 512 + skq;
    u16* lA0 = Al + 512 * w;
    u16* lA1 = Al + 2048 + 512 * w;
    u16* lB0 = Bl + 512 * w;
    u16* lB1 = Bl + 2048 + 512 * w;
    f32x4 acca[4][2], accg[4][2];
#pragma unroll
    for (int i = 0; i < 4; i++)
#pragma unroll
        for (int j = 0; j < 2; j++)
#pragma unroll
            for (int e = 0; e < 4; e++) { acca[i][j][e] = 0.f; accg[i][j][e] = 0.f; }
    for (int k0 = 0; k0 < 512; k0 += 32) {
        __syncthreads();
        gl16(Ap0 + k0, lA0);
        gl16(Ap1 + k0, lA1);
        gl16(Wa + k0, lB0);
        gl16(Wg + k0, lB1);
        __syncthreads();
        bf16x8 av[4], ba[2], bg[2];
#pragma unroll
        for (int mi = 0; mi < 4; mi++)
            av[mi] = *(const bf16x8*)&Al[(wm * 64 + mi * 16 + lr) * 32 + hi * 8];
#pragma unroll
        for (int nj = 0; nj < 2; nj++) {
            ba[nj] = *(const bf16x8*)&Bl[(wn * 32 + nj * 16 + lr) * 32 + hi * 8];
            bg[nj] = *(const bf16x8*)&Bl[(wn * 32 + nj * 16 + lr + 64) * 32 + hi * 8];
        }
#pragma unroll
        for (int mi = 0; mi < 4; mi++)
#pragma unroll
            for (int nj = 0; nj < 2; nj++) {
                acca[mi][nj] = mfma32(av[mi], ba[nj], acca[mi][nj]);
                accg[mi][nj] = mfma32(av[mi], bg[nj], accg[mi][nj]);
            }
    }
#pragma unroll
    for (int mi = 0; mi < 4; mi++)
#pragma unroll
        for (int nj = 0; nj < 2; nj++) {
            const int c = bn + wn * 32 + nj * 16 + lr;
#pragma unroll
            for (int j = 0; j < 4; j++) {
                const int r = bm + wm * 64 + mi * 16 + hi * 4 + j;
                const float a = acca[mi][nj][j] + b1[c];
                const float g = accg[mi][nj][j] + b1[2048 + c];
                const float ge = 0.5f * g * (1.f + erff(g * 0.70710678118654752f));
                ag[(size_t)r * 2048 + c] = f2b(a * ge);
            }
        }
}

// ---------------- attention: 2-way split-K (r14-exact) ----------------------
__global__ __launch_bounds__(256) void k_mattn(
    const u16* __restrict__ q, const u16* __restrict__ kbuf,
    const u16* __restrict__ vT, const float* __restrict__ tab,
    u16* __restrict__ ao, const int rowbase)
{
    __shared__ float mrg[2][64][37];
    const int bid = blockIdx.x, tid = threadIdx.x;
    const int h = bid & 7, qi = bid >> 3;
    const int qbase = qi << 6;
    const int w = tid >> 6, l = tid & 63;
    const int p = w >> 1, ko = (w & 1) << 9;            // key offset 0 / 512
    const int lr = l & 15, hi = l >> 4;
    const int qrA = qbase + p * 32 + lr;
    const int qrB = qrA + 16;
    const int b = (rowbase + qbase) >> 12;              // batch
    const bf16x8 qfA0 = *(const bf16x8*)&q[(size_t)qrA * 512 + h * 64 + hi * 8];
    const bf16x8 qfA1 = *(const bf16x8*)&q[(size_t)qrA * 512 + h * 64 + hi * 8 + 32];
    const bf16x8 qfB0 = *(const bf16x8*)&q[(size_t)qrB * 512 + h * 64 + hi * 8];
    const bf16x8 qfB1 = *(const bf16x8*)&q[(size_t)qrB * 512 + h * 64 + hi * 8 + 32];
    const u16* Kp = kbuf + (size_t)b * 524288 + h * 64;
    const u16* Vp = vT + ((size_t)(b * 8 + h)) * 65536;
    const int g2 = (hi & 1) * 2;
    const int srcA = lr + (g2 << 4);
    const int srcB = srcA + 16;
    const bool up = (hi >> 1) != 0;
    f32x4 accA[4], accB[4];
#pragma unroll
    for (int dj = 0; dj < 4; dj++)
#pragma unroll
        for (int e = 0; e < 4; e++) { accA[dj][e] = 0.f; accB[dj][e] = 0.f; }
    float mA = -1e30f, lA = 0.f, mB = -1e30f, lB = 0.f;
    for (int kk = 0; kk < 512; kk += 64) {
        const int kc = ko + kk;
        f32x4 stA[4], stB[4];
#pragma unroll
        for (int t = 0; t < 4; t++) {
            const size_t krow = (size_t)(kc + t * 16 + lr) * 512 + hi * 8;
            const bf16x8 kf0 = *(const bf16x8*)&Kp[krow];
            const bf16x8 kf1 = *(const bf16x8*)&Kp[krow + 32];
#pragma unroll
            for (int e = 0; e < 4; e++) { stA[t][e] = 0.f; stB[t][e] = 0.f; }
            stA[t] = mfma32(kf0, qfA0, stA[t]);
            stA[t] = mfma32(kf1, qfA1, stA[t]);
            stB[t] = mfma32(kf0, qfB0, stB[t]);
            stB[t] = mfma32(kf1, qfB1, stB[t]);
        }
        // hoist V fragments: loads overlap the softmax chains below
        bf16x8 vf[4][2];
#pragma unroll
        for (int dj = 0; dj < 4; dj++)
#pragma unroll
            for (int ks = 0; ks < 2; ks++)
                vf[dj][ks] = *(const bf16x8*)
                    &Vp[(size_t)(dj * 16 + lr) * 1024 + kc + ks * 32 + hi * 8];
        // ---- softmax group A ----
        bf16x8 pfragA[2], pfragB[2];
        {
            float mx = -1e30f;
#pragma unroll
            for (int t = 0; t < 4; t++)
#pragma unroll
                for (int j = 0; j < 4; j++) mx = fmaxf(mx, stA[t][j]);
            mx = fmaxf(mx, __shfl_xor(mx, 16));
            mx = fmaxf(mx, __shfl_xor(mx, 32));
            if (!__all(mx - mA <= 8.f)) {
                const float mnew = fmaxf(mA, mx);
                const float alpha = __expf(mA - mnew);
                lA *= alpha;
#pragma unroll
                for (int dj = 0; dj < 4; dj++)
#pragma unroll
                    for (int e = 0; e < 4; e++) accA[dj][e] *= alpha;
                mA = mnew;
            }
            float ps = 0.f;
            unsigned P64[4][2];
#pragma unroll
            for (int t = 0; t < 4; t++) {
                const float p0 = __expf(stA[t][0] - mA);
                const float p1 = __expf(stA[t][1] - mA);
                const float p2 = __expf(stA[t][2] - mA);
                const float p3 = __expf(stA[t][3] - mA);
                ps += (p0 + p1) + (p2 + p3);
                P64[t][0] = cvtpk(p0, p1);
                P64[t][1] = cvtpk(p2, p3);
            }
            ps += __shfl_xor(ps, 16);
            ps += __shfl_xor(ps, 32);
            lA += ps;
#pragma unroll
            for (int ks = 0; ks < 2; ks++) {
                const unsigned c0x = P64[ks * 2 + 0][0], c0y = P64[ks * 2 + 0][1];
                const unsigned c1x = P64[ks * 2 + 1][0], c1y = P64[ks * 2 + 1][1];
                const unsigned a0x = (unsigned)__shfl((int)c0x, srcA);
                const unsigned a0y = (unsigned)__shfl((int)c0y, srcA);
                const unsigned a1x = (unsigned)__shfl((int)c1x, srcA);
                const unsigned a1y = (unsigned)__shfl((int)c1y, srcA);
                const unsigned b0x = (unsigned)__shfl((int)c0x, srcB);
                const unsigned b0y = (unsigned)__shfl((int)c0y, srcB);
                const unsigned b1x = (unsigned)__shfl((int)c1x, srcB);
                const unsigned b1y = (unsigned)__shfl((int)c1y, srcB);
                union { unsigned u[4]; bf16x8 v; } pk;
                pk.u[0] = up ? a1x : a0x;
                pk.u[1] = up ? a1y : a0y;
                pk.u[2] = up ? b1x : b0x;
                pk.u[3] = up ? b1y : b0y;
                pfragA[ks] = pk.v;
            }
        }
        // ---- softmax group B ----
        {
            float mx = -1e30f;
#pragma unroll
            for (int t = 0; t < 4; t++)
#pragma unroll
                for (int j = 0; j < 4; j++) mx = fmaxf(mx, stB[t][j]);
            mx = fmaxf(mx, __shfl_xor(mx, 16));
            mx = fmaxf(mx, __shfl_xor(mx, 32));
            if (!__all(mx - mB <= 8.f)) {
                const float mnew = fmaxf(mB, mx);
                const float alpha = __expf(mB - mnew);
                lB *= alpha;
#pragma unroll
                for (int dj = 0; dj < 4; dj++)
#pragma unroll
                    for (int e = 0; e < 4; e++) accB[dj][e] *= alpha;
                mB = mnew;
            }
            float ps = 0.f;
            unsigned P64[4][2];
#pragma unroll
            for (int t = 0; t < 4; t++) {
                const float p0 = __expf(stB[t][0] - mB);
                const float p1 = __expf(stB[t][1] - mB);
                const float p2 = __expf(stB[t][2] - mB);
                const float p3 = __expf(stB[t][3] - mB);
                ps += (p0 + p1) + (p2 + p3);
                P64[t][0] = cvtpk(p0, p1);
                P64[t][1] = cvtpk(p2, p3);
            }
            ps += __shfl_xor(ps, 16);
            ps += __shfl_xor(ps, 32);
            lB += ps;
#pragma unroll
            for (int ks = 0; ks < 2; ks++) {
                const unsigned c0x = P64[ks * 2 + 0][0], c0y = P64[ks * 2 + 0][1];
                const unsigned c1x = P64[ks * 2 + 1][0], c1y = P64[ks * 2 + 1][1];
                const unsigned a0x = (unsigned)__shfl((int)c0x, srcA);
                const unsigned a0y = (unsigned)__shfl((int)c0y, srcA);
                const unsigned a1x = (unsigned)__shfl((int)c1x, srcA);
                const unsigned a1y = (unsigned)__shfl((int)c1y, srcA);
                const unsigned b0x = (unsigned)__shfl((int)c0x, srcB);
                const unsigned b0y = (unsigned)__shfl((int)c0y, srcB);
                const unsigned b1x = (unsigned)__shfl((int)c1x, srcB);
                const unsigned b1y = (unsigned)__shfl((int)c1y, srcB);
                union { unsigned u[4]; bf16x8 v; } pk;
                pk.u[0] = up ? a1x : a0x;
                pk.u[1] = up ? a1y : a0y;
                pk.u[2] = up ? b1x : b0x;
                pk.u[3] = up ? b1y : b0y;
                pfragB[ks] = pk.v;
            }
        }
        // ---- PV ----
#pragma unroll
        for (int dj = 0; dj < 4; dj++)
#pragma unroll
            for (int ks = 0; ks < 2; ks++) {
                accA[dj] = mfma32(vf[dj][ks], pfragA[ks], accA[dj]);
                accB[dj] = mfma32(vf[dj][ks], pfragB[ks], accB[dj]);
            }
    }
    // ---- split-K merge: odd wave publishes, even wave merges + writes ------
    if (w & 1) {
        float* dst = mrg[p][l];
        dst[0] = mA; dst[1] = lA; dst[2] = mB; dst[3] = lB;
#pragma unroll
        for (int dj = 0; dj < 4; dj++)
#pragma unroll
            for (int e = 0; e < 4; e++) {
                dst[4 + dj * 4 + e]  = accA[dj][e];
                dst[20 + dj * 4 + e] = accB[dj][e];
            }
    }
    __syncthreads();
    if (w & 1) return;
    {
        const float* src = mrg[p][l];
        const float m1A = src[0], l1A = src[1], m1B = src[2], l1B = src[3];
        {
            const float mm = fmaxf(mA, m1A);
            const float f0 = __expf(mA - mm), f1 = __expf(m1A - mm);
            lA = lA * f0 + l1A * f1;
#pragma unroll
            for (int dj = 0; dj < 4; dj++)
#pragma unroll
                for (int e = 0; e < 4; e++)
                    accA[dj][e] = accA[dj][e] * f0 + src[4 + dj * 4 + e] * f1;
        }
        {
            const float mm = fmaxf(mB, m1B);
            const float f0 = __expf(mB - mm), f1 = __expf(m1B - mm);
            lB = lB * f0 + l1B * f1;
#pragma unroll
            for (int dj = 0; dj < 4; dj++)
#pragma unroll
                for (int e = 0; e < 4; e++)
                    accB[dj][e] = accB[dj][e] * f0 + src[20 + dj * 4 + e] * f1;
        }
    }
    const float ivA = 1.f / lA, ivB = 1.f / lB;
#pragma unroll
    for (int g = 0; g < 2; g++) {
        const int qr = g ? qrB : qrA;
        const float invl = g ? ivB : ivA;
#pragma unroll
        for (int dj = 0; dj < 4; dj++) {
            const f32x4 a = g ? accB[dj] : accA[dj];
            const int d0 = dj * 16 + hi * 4;
            float y[4];
#pragma unroll
            for (int pp = 0; pp < 2; pp++) {
                const float x0 = a[2 * pp] * invl;
                const float x1 = a[2 * pp + 1] * invl;
                const int ii = (d0 >> 1) + pp;
                if (ii < 16) {
                    const float cc = tab[((size_t)qr << 5) + (ii << 1)];
                    const float ss = tab[((size_t)qr << 5) + (ii << 1) + 1];
                    y[2 * pp]     = fmaf(x0, cc, x1 * ss);    // inverse rotation
                    y[2 * pp + 1] = fmaf(x1, cc, -x0 * ss);
                } else {
                    y[2 * pp] = x0; y[2 * pp + 1] = x1;
                }
            }
            ushort4 o;
            o.x = f2b(y[0]); o.y = f2b(y[1]); o.z = f2b(y[2]); o.w = f2b(y[3]);
            *(ushort4*)&ao[(size_t)qr * 512 + h * 64 + d0] = o;
        }
    }
}

// ---------------- final: LN + dot with wproj (bf16 in, f32 out) -------------
__global__ __launch_bounds__(128) void k_final(
    const u16* __restrict__ dec, const float* __restrict__ w,
    const float* __restrict__ bb, const float* __restrict__ wproj,
    const float* __restrict__ bproj, float* __restrict__ out)
{
    const int r = blockIdx.x, tid = threadIdx.x, c0 = tid << 2;
    const ushort4 xi = *(const ushort4*)&dec[(size_t)r * 512 + c0];
    float4 x;
    x.x = b2f(xi.x); x.y = b2f(xi.y); x.z = b2f(xi.z); x.w = b2f(xi.w);
    float s  = x.x + x.y + x.z + x.w;
    float s2 = x.x * x.x + x.y * x.y + x.z * x.z + x.w * x.w;
#pragma unroll
    for (int o = 32; o > 0; o >>= 1) { s += __shfl_down(s, o); s2 += __shfl_down(s2, o); }
    __shared__ float buf[4];
    if ((tid & 63) == 0) { buf[(tid >> 6) << 1] = s; buf[((tid >> 6) << 1) + 1] = s2; }
    __syncthreads();
    s = buf[0] + buf[2]; s2 = buf[1] + buf[3];
    const float mu = s * (1.f / 512.f);
    const float rs = rsqrtf(s2 * (1.f / 512.f) - mu * mu + 1e-5f);
    const float4 w4 = *(const float4*)&w[c0];
    const float4 b4 = *(const float4*)&bb[c0];
    const float4 p4 = *(const float4*)&wproj[c0];
    float part = ((x.x - mu) * rs * w4.x + b4.x) * p4.x
               + ((x.y - mu) * rs * w4.y + b4.y) * p4.y
               + ((x.z - mu) * rs * w4.z + b4.z) * p4.z
               + ((x.w - mu) * rs * w4.w + b4.w) * p4.w;
#pragma unroll
    for (int o = 32; o > 0; o >>= 1) part += __shfl_down(part, o);
    __shared__ float buf2[2];
    if ((tid & 63) == 0) buf2[tid >> 6] = part;
    __syncthreads();
    if (tid == 0) out[r] = buf2[0] + buf2[1] + bproj[0];
}

// ---------------------------------------------------------------------------
extern "C" void kernel_launch(void* const* d_in, const int* in_sizes, int n_in,
                              void* d_out, int out_size, void* d_ws, size_t ws_size,
                              hipStream_t stream)
{
    (void)in_sizes; (void)n_in; (void)out_size;
    const float* enc  = (const float*)d_in[0];
    const float* lts  = (const float*)d_in[1];
    const int*   qidx = (const int*)  d_in[2];
    const float* qts  = (const float*)d_in[3];
    const float* uemb = (const float*)d_in[4];
    const float* vpb  = (const float*)d_in[6];
    const float* canw = (const float*)d_in[7];
    const float* canb = (const float*)d_in[8];
    const float* ccw  = (const float*)d_in[9];
    const float* ccb  = (const float*)d_in[10];
    const float* wq   = (const float*)d_in[11];
    const float* wkv  = (const float*)d_in[12];
    const float* wo   = (const float*)d_in[13];
    const float* bo   = (const float*)d_in[14];
    const float* flnw = (const float*)d_in[15];
    const float* flnb = (const float*)d_in[16];
    const float* w1   = (const float*)d_in[17];
    const float* b1   = (const float*)d_in[18];
    const float* w2   = (const float*)d_in[19];
    const float* b2   = (const float*)d_in[20];
    const float* olnw = (const float*)d_in[21];
    const float* olnb = (const float*)d_in[22];
    const float* wpj  = (const float*)d_in[23];
    const float* bpj  = (const float*)d_in[24];
    float* outp = (float*)d_out;

    // workspace: f32 tabs, then bf16 region
    float* tabq = (float*)d_ws;              // 16384*32
    float* tabl = tabq + 524288;             // 4096*32
    u16* wqb  = (u16*)(tabl + 131072);       // 512*512
    u16* wkvb = wqb + 262144;                // 1024*512
    u16* wob  = wkvb + 524288;               // 512*512
    u16* w1b  = wob + 262144;                // 4096*512
    u16* w2b  = w1b + 2097152;               // 512*2048
    u16* cn   = w2b + 1048576;               // 4096*512
    u16* kb   = cn + 2097152;                // 4096*512
    u16* vT   = kb + 2097152;                // 4*8*64*1024
    const size_t base_b = 2621440ull + 20971520ull;       // tabs + bf16 shared
    int CQ = 16384;
    while (CQ > 512 &&
           base_b + (size_t)CQ * 5120 + (size_t)(CQ < 4096 ? CQ : 4096) * 4096 > ws_size)
        CQ >>= 1;
    int SF = CQ;
    while (SF > 512 && base_b + (size_t)CQ * 5120 + (size_t)SF * 4096 > ws_size)
        SF >>= 1;
    u16* qtokC = vT + 2097152;               // CQ*512
    u16* xnC   = qtokC + (size_t)CQ * 512;   // CQ*512 (reused: ln_dec)
    u16* qC    = xnC + (size_t)CQ * 512;     // CQ*512 (reused: dec_final)
    u16* aoC   = qC + (size_t)CQ * 512;      // CQ*512
    u16* d2C   = aoC + (size_t)CQ * 512;     // CQ*512
    u16* agC   = d2C + (size_t)CQ * 512;     // SF*2048

    k_cvt<<<256, 256, 0, stream>>>(wq, wqb, 262144);
    k_cvt<<<512, 256, 0, stream>>>(wkv, wkvb, 524288);
    k_cvt<<<256, 256, 0, stream>>>(wo, wob, 262144);
    k_cvt<<<2048, 256, 0, stream>>>(w1, w1b, 2097152);
    k_cvt<<<1024, 256, 0, stream>>>(w2, w2b, 1048576);
    k_rope_tab16<<<1024, 256, 0, stream>>>(qts, tabq, 16384);
    k_rope_tab16<<<256, 256, 0, stream>>>(lts, tabl, 4096);
    k_ln_f<<<4096, 128, 0, stream>>>(enc, ccw, ccb, cn);
    k_mgemm<1><<<dim3(8, 32), 256, 0, stream>>>(cn, wkvb, 1024, 512,
                                                kb, vT, nullptr, nullptr, tabl);

    for (int g0 = 0; g0 < 16384; g0 += CQ) {
        const float* tabc = tabq + (size_t)g0 * 32;
        k_qtok_ln<<<CQ, 128, 0, stream>>>(qidx + g0, uemb, vpb, canw, canb,
                                          qtokC, xnC);
        k_mgemm64<0><<<dim3(8, CQ / 128), 256, 0, stream>>>(xnC, wqb, 512,
                                                            qC, nullptr, nullptr, tabc);
        k_mattn<<<(CQ / 64) * 8, 256, 0, stream>>>(qC, kb, vT, tabc, aoC, g0);
        k_mgemm64<2><<<dim3(8, CQ / 128), 256, 0, stream>>>(aoC, wob, 512,
                                                            d2C, bo, qtokC, nullptr);
        k_ln_h<<<CQ, 128, 0, stream>>>(d2C, flnw, flnb, xnC);
        for (int f0 = 0; f0 < CQ; f0 += SF) {
            k_mffn1<<<dim3(32, SF / 128), 256, 0, stream>>>(xnC + (size_t)f0 * 512,
                                                            w1b, b1, agC);
            k_mgemm64<2><<<dim3(8, SF / 128), 256, 0, stream>>>(agC, w2b, 2048,
                                                                qC + (size_t)f0 * 512,
                                                                b2, d2C + (size_t)f0 * 512, nullptr);
            k_final<<<SF, 128, 0, stream>>>(qC + (size_t)f0 * 512, olnw, olnb,
                                            wpj, bpj, outp + g0 + f0);
        }
    }
}

// Round 18
// 400.120 us; speedup vs baseline: 1.0201x; 1.0201x over previous
//
#include <hip/hip_runtime.h>
#include <math.h>

// ---------------------------------------------------------------------------
// MaskingDecoder bf16-MFMA v14-final (r16-exact, session best 400us):
//  - GEMMs: 128x128 tile, gl16 staging, XCD-aware block swizzle
//  - FFN1: 128x64 dual-acc GEGLU
//  - attention: 2-way split-K, XCD-local heads, in-register softmax (cvtpk),
//    defer-max, shared K/V loads across dual q-groups, LDS merge
// ---------------------------------------------------------------------------

typedef unsigned short u16;
typedef __attribute__((ext_vector_type(8))) short bf16x8;
typedef __attribute__((ext_vector_type(4))) float f32x4;

__device__ __forceinline__ u16 f2b(float x) {
    union { float f; unsigned u; } v; v.f = x;
    unsigned r = v.u + 0x7fffu + ((v.u >> 16) & 1u);
    return (u16)(r >> 16);
}
__device__ __forceinline__ float b2f(u16 h) {
    union { unsigned u; float f; } v; v.u = ((unsigned)h) << 16;
    return v.f;
}
__device__ __forceinline__ unsigned cvtpk(float lo, float hi) {
    unsigned r;
    asm("v_cvt_pk_bf16_f32 %0, %1, %2" : "=v"(r) : "v"(lo), "v"(hi));
    return r;
}
__device__ __forceinline__ f32x4 mfma32(bf16x8 a, bf16x8 b, f32x4 c) {
    return __builtin_amdgcn_mfma_f32_16x16x32_bf16(a, b, c, 0, 0, 0);
}
// async global->LDS, 16B per lane; LDS base wave-uniform, dest = base+lane*16
__device__ __forceinline__ void gl16(const u16* g, u16* l) {
    __builtin_amdgcn_global_load_lds((const __attribute__((address_space(1))) void*)g,
                                     (__attribute__((address_space(3))) void*)l,
                                     16, 0, 0);
}
// XCD-aware swizzle of the linear block id (bijective when nwg % 8 == 0)
__device__ __forceinline__ int xcd_swz(int lin, int nwg) {
    return ((nwg & 7) == 0) ? ((lin & 7) * (nwg >> 3) + (lin >> 3)) : lin;
}

// ---------------- f32 -> bf16 weight convert --------------------------------
__global__ __launch_bounds__(256) void k_cvt(const float* __restrict__ in,
                                             u16* __restrict__ out, const int n)
{
    const int i = (blockIdx.x * 256 + threadIdx.x) * 4;
    if (i >= n) return;
    const float4 v = *(const float4*)&in[i];
    ushort4 o;
    o.x = f2b(v.x); o.y = f2b(v.y); o.z = f2b(v.z); o.w = f2b(v.w);
    *(ushort4*)&out[i] = o;
}

// ---------------- rope table: 16 (cos,sin) pairs per row --------------------
__global__ void k_rope_tab16(const float* __restrict__ t, float* __restrict__ tab,
                             const int n)
{
    const int idx = blockIdx.x * 256 + threadIdx.x;
    if (idx >= n * 16) return;
    const int r = idx >> 4, i = idx & 15;
    const float b0 = (float)(1e-4 / 2.0627);
    const float a0 = (float)(2.0 * 3.14159265358979323846 / 1e-4);
    const float invf = a0 * (float)pow((double)b0, (double)i * (1.0 / 16.0));
    const float ang = t[r] * invf;
    float sn, cs;
    sincosf(ang, &sn, &cs);
    tab[((size_t)r << 5) + (i << 1)]     = cs;
    tab[((size_t)r << 5) + (i << 1) + 1] = sn;
}

// ---------------- qtok build + layernorm -> bf16 ----------------------------
__global__ __launch_bounds__(128) void k_qtok_ln(
    const int* __restrict__ qidx, const float* __restrict__ uemb,
    const float* __restrict__ vpb, const float* __restrict__ w,
    const float* __restrict__ bb, u16* __restrict__ qtok, u16* __restrict__ xn)
{
    const int r = blockIdx.x, tid = threadIdx.x, c0 = tid << 2;
    float4 x;
    if (c0 < 256) {
        x = *(const float4*)&vpb[c0];
    } else {
        const int u = qidx[r];
        x = *(const float4*)&uemb[(size_t)u * 256 + (c0 - 256)];
    }
    ushort4 qo;
    qo.x = f2b(x.x); qo.y = f2b(x.y); qo.z = f2b(x.z); qo.w = f2b(x.w);
    *(ushort4*)&qtok[(size_t)r * 512 + c0] = qo;
    float s  = x.x + x.y + x.z + x.w;
    float s2 = x.x * x.x + x.y * x.y + x.z * x.z + x.w * x.w;
#pragma unroll
    for (int o = 32; o > 0; o >>= 1) { s += __shfl_down(s, o); s2 += __shfl_down(s2, o); }
    __shared__ float buf[4];
    if ((tid & 63) == 0) { buf[(tid >> 6) << 1] = s; buf[((tid >> 6) << 1) + 1] = s2; }
    __syncthreads();
    s = buf[0] + buf[2]; s2 = buf[1] + buf[3];
    const float mu = s * (1.f / 512.f);
    const float rs = rsqrtf(s2 * (1.f / 512.f) - mu * mu + 1e-5f);
    const float4 w4 = *(const float4*)&w[c0];
    const float4 b4 = *(const float4*)&bb[c0];
    ushort4 yo;
    yo.x = f2b((x.x - mu) * rs * w4.x + b4.x);
    yo.y = f2b((x.y - mu) * rs * w4.y + b4.y);
    yo.z = f2b((x.z - mu) * rs * w4.z + b4.z);
    yo.w = f2b((x.w - mu) * rs * w4.w + b4.w);
    *(ushort4*)&xn[(size_t)r * 512 + c0] = yo;
}

// ---------------- layernorm f32-in -> bf16-out ------------------------------
__global__ __launch_bounds__(128) void k_ln_f(
    const float* __restrict__ in, const float* __restrict__ w,
    const float* __restrict__ bb, u16* __restrict__ outp)
{
    const int r = blockIdx.x, tid = threadIdx.x, c0 = tid << 2;
    const float4 x = *(const float4*)&in[(size_t)r * 512 + c0];
    float s  = x.x + x.y + x.z + x.w;
    float s2 = x.x * x.x + x.y * x.y + x.z * x.z + x.w * x.w;
#pragma unroll
    for (int o = 32; o > 0; o >>= 1) { s += __shfl_down(s, o); s2 += __shfl_down(s2, o); }
    __shared__ float buf[4];
    if ((tid & 63) == 0) { buf[(tid >> 6) << 1] = s; buf[((tid >> 6) << 1) + 1] = s2; }
    __syncthreads();
    s = buf[0] + buf[2]; s2 = buf[1] + buf[3];
    const float mu = s * (1.f / 512.f);
    const float rs = rsqrtf(s2 * (1.f / 512.f) - mu * mu + 1e-5f);
    const float4 w4 = *(const float4*)&w[c0];
    const float4 b4 = *(const float4*)&bb[c0];
    ushort4 yo;
    yo.x = f2b((x.x - mu) * rs * w4.x + b4.x);
    yo.y = f2b((x.y - mu) * rs * w4.y + b4.y);
    yo.z = f2b((x.z - mu) * rs * w4.z + b4.z);
    yo.w = f2b((x.w - mu) * rs * w4.w + b4.w);
    *(ushort4*)&outp[(size_t)r * 512 + c0] = yo;
}

// ---------------- layernorm bf16-in -> bf16-out -----------------------------
__global__ __launch_bounds__(128) void k_ln_h(
    const u16* __restrict__ in, const float* __restrict__ w,
    const float* __restrict__ bb, u16* __restrict__ outp)
{
    const int r = blockIdx.x, tid = threadIdx.x, c0 = tid << 2;
    const ushort4 xi = *(const ushort4*)&in[(size_t)r * 512 + c0];
    float4 x;
    x.x = b2f(xi.x); x.y = b2f(xi.y); x.z = b2f(xi.z); x.w = b2f(xi.w);
    float s  = x.x + x.y + x.z + x.w;
    float s2 = x.x * x.x + x.y * x.y + x.z * x.z + x.w * x.w;
#pragma unroll
    for (int o = 32; o > 0; o >>= 1) { s += __shfl_down(s, o); s2 += __shfl_down(s2, o); }
    __shared__ float buf[4];
    if ((tid & 63) == 0) { buf[(tid >> 6) << 1] = s; buf[((tid >> 6) << 1) + 1] = s2; }
    __syncthreads();
    s = buf[0] + buf[2]; s2 = buf[1] + buf[3];
    const float mu = s * (1.f / 512.f);
    const float rs = rsqrtf(s2 * (1.f / 512.f) - mu * mu + 1e-5f);
    const float4 w4 = *(const float4*)&w[c0];
    const float4 b4 = *(const float4*)&bb[c0];
    ushort4 yo;
    yo.x = f2b((x.x - mu) * rs * w4.x + b4.x);
    yo.y = f2b((x.y - mu) * rs * w4.y + b4.y);
    yo.z = f2b((x.z - mu) * rs * w4.z + b4.z);
    yo.w = f2b((x.w - mu) * rs * w4.w + b4.w);
    *(ushort4*)&outp[(size_t)r * 512 + c0] = yo;
}

// ---------------- MFMA GEMM: C[m,n] = sum_k A[m,k]*W[n,k] -------------------
// 128x128 tile, BK=32, 4 waves (2x2), global_load_lds(16B) staging.
// Blocks XCD-swizzled: contiguous tile-chunk per XCD (L2-resident panels).
// EPI 0: rope(tab) -> out0 bf16
// EPI 1: rope(tab); c<512 -> out0 (k, pre-scaled by 1/8); c>=512 -> out1 (vT)
// EPI 2: out0 = acc + bias + res (bf16 residual add)
template <int EPI>
__global__ __launch_bounds__(256) void k_mgemm(
    const u16* __restrict__ A, const u16* __restrict__ W,
    const int N, const int K,
    u16* __restrict__ out0, u16* __restrict__ out1,
    const float* __restrict__ bias, const u16* __restrict__ res,
    const float* __restrict__ tab)
{
    __shared__ u16 Al[128 * 32];
    __shared__ u16 Bl[128 * 32];
    const int lin = blockIdx.x + gridDim.x * blockIdx.y;
    const int nwg = gridDim.x * gridDim.y;
    const int swz = xcd_swz(lin, nwg);
    const int bxx = swz % gridDim.x, byy = swz / gridDim.x;
    const int bm = byy << 7, bn = bxx << 7;
    const int tid = threadIdx.x;
    const int w = tid >> 6, l = tid & 63;
    const int wm = w >> 1, wn = w & 1;
    const int lr = l & 15, hi = l >> 4;
    const int srow = l >> 2, skq = (l & 3) << 3;
    const u16* Ap0 = A + (size_t)(bm + 16 * w + srow) * K + skq;
    const u16* Ap1 = A + (size_t)(bm + 64 + 16 * w + srow) * K + skq;
    const u16* Wp0 = W + (size_t)(bn + 16 * w + srow) * K + skq;
    const u16* Wp1 = W + (size_t)(bn + 64 + 16 * w + srow) * K + skq;
    u16* lA0 = Al + 512 * w;
    u16* lA1 = Al + 2048 + 512 * w;
    u16* lB0 = Bl + 512 * w;
    u16* lB1 = Bl + 2048 + 512 * w;
    f32x4 acc[4][4];
#pragma unroll
    for (int i = 0; i < 4; i++)
#pragma unroll
        for (int j = 0; j < 4; j++)
#pragma unroll
            for (int e = 0; e < 4; e++) acc[i][j][e] = 0.f;
    for (int k0 = 0; k0 < K; k0 += 32) {
        __syncthreads();                 // WAR: prev iter's LDS reads done
        gl16(Ap0 + k0, lA0);
        gl16(Ap1 + k0, lA1);
        gl16(Wp0 + k0, lB0);
        gl16(Wp1 + k0, lB1);
        __syncthreads();                 // RAW: vmcnt drained, tile ready
        bf16x8 av[4], bv[4];
#pragma unroll
        for (int mi = 0; mi < 4; mi++)
            av[mi] = *(const bf16x8*)&Al[(wm * 64 + mi * 16 + lr) * 32 + hi * 8];
#pragma unroll
        for (int nj = 0; nj < 4; nj++)
            bv[nj] = *(const bf16x8*)&Bl[(wn * 64 + nj * 16 + lr) * 32 + hi * 8];
#pragma unroll
        for (int mi = 0; mi < 4; mi++)
#pragma unroll
            for (int nj = 0; nj < 4; nj++)
                acc[mi][nj] = mfma32(av[mi], bv[nj], acc[mi][nj]);
    }
#pragma unroll
    for (int mi = 0; mi < 4; mi++) {
#pragma unroll
        for (int nj = 0; nj < 4; nj++) {
            const int c = bn + wn * 64 + nj * 16 + lr;
#pragma unroll
            for (int j = 0; j < 4; j++) {
                const int r = bm + wm * 64 + mi * 16 + hi * 4 + j;
                const float x = acc[mi][nj][j];
                if (EPI == 2) {
                    const float y = x + bias[c] + b2f(res[(size_t)r * 512 + c]);
                    out0[(size_t)r * 512 + c] = f2b(y);
                } else {
                    const float p = __shfl_xor(x, 1);
                    const int ci = c & 63;
                    float y = x;
                    if (ci < 32) {
                        const int ii = ci >> 1;
                        const float cc = tab[((size_t)r << 5) + (ii << 1)];
                        const float ss = tab[((size_t)r << 5) + (ii << 1) + 1];
                        y = (c & 1) ? fmaf(x, cc, p * ss) : fmaf(x, cc, -p * ss);
                    }
                    if (EPI == 0) {
                        out0[(size_t)r * 512 + c] = f2b(y);
                    } else {
                        if (c < 512) {
                            out0[(size_t)r * 512 + c] = f2b(y * 0.125f);  // fold DH^-0.5
                        } else {
                            const int d = c - 512, hh = d >> 6, dd = d & 63;
                            const int bq = r >> 10, pos = r & 1023;
                            out1[(((size_t)(bq * 8 + hh)) * 64 + dd) * 1024 + pos] = f2b(y);
                        }
                    }
                }
            }
        }
    }
}

// ---------------- FFN1 (r12-proven): 128 rows x 64 ag-cols, XCD-swizzled ----
__global__ __launch_bounds__(256) void k_mffn1(
    const u16* __restrict__ A, const u16* __restrict__ W1,
    const float* __restrict__ b1, u16* __restrict__ ag)
{
    __shared__ u16 Al[128 * 32];
    __shared__ u16 Bl[128 * 32];
    const int lin = blockIdx.x + gridDim.x * blockIdx.y;
    const int nwg = gridDim.x * gridDim.y;
    const int swz = xcd_swz(lin, nwg);
    const int bxx = swz % gridDim.x, byy = swz / gridDim.x;
    const int bm = byy << 7, bn = bxx << 6;
    const int tid = threadIdx.x;
    const int w = tid >> 6, l = tid & 63;
    const int wm = w >> 1, wn = w & 1;
    const int lr = l & 15, hi = l >> 4;
    const int srow = l >> 2, skq = (l & 3) << 3;
    const u16* Ap0 = A  + (size_t)(bm + 16 * w + srow) * 512 + skq;
    const u16* Ap1 = A  + (size_t)(bm + 64 + 16 * w + srow) * 512 + skq;
    const u16* Wa  = W1 + (size_t)(bn + 16 * w + srow) * 512 + skq;
    const u16* Wg  = W1 + (size_t)(2048 + bn + 16 * w + srow) * 512 + skq;
    u16* lA0 = Al + 512 * w;
    u16* lA1 = Al + 2048 + 512 * w;
    u16* lB0 = Bl + 512 * w;
    u16* lB1 = Bl + 2048 + 512 * w;
    f32x4 acca[4][2], accg[4][2];
#pragma unroll
    for (int i = 0; i < 4; i++)
#pragma unroll
        for (int j = 0; j < 2; j++)
#pragma unroll
            for (int e = 0; e < 4; e++) { acca[i][j][e] = 0.f; accg[i][j][e] = 0.f; }
    for (int k0 = 0; k0 < 512; k0 += 32) {
        __syncthreads();
        gl16(Ap0 + k0, lA0);
        gl16(Ap1 + k0, lA1);
        gl16(Wa + k0, lB0);
        gl16(Wg + k0, lB1);
        __syncthreads();
        bf16x8 av[4], ba[2], bg[2];
#pragma unroll
        for (int mi = 0; mi < 4; mi++)
            av[mi] = *(const bf16x8*)&Al[(wm * 64 + mi * 16 + lr) * 32 + hi * 8];
#pragma unroll
        for (int nj = 0; nj < 2; nj++) {
            ba[nj] = *(const bf16x8*)&Bl[(wn * 32 + nj * 16 + lr) * 32 + hi * 8];
            bg[nj] = *(const bf16x8*)&Bl[(wn * 32 + nj * 16 + lr + 64) * 32 + hi * 8];
        }
#pragma unroll
        for (int mi = 0; mi < 4; mi++)
#pragma unroll
            for (int nj = 0; nj < 2; nj++) {
                acca[mi][nj] = mfma32(av[mi], ba[nj], acca[mi][nj]);
                accg[mi][nj] = mfma32(av[mi], bg[nj], accg[mi][nj]);
            }
    }
#pragma unroll
    for (int mi = 0; mi < 4; mi++)
#pragma unroll
        for (int nj = 0; nj < 2; nj++) {
            const int c = bn + wn * 32 + nj * 16 + lr;
#pragma unroll
            for (int j = 0; j < 4; j++) {
                const int r = bm + wm * 64 + mi * 16 + hi * 4 + j;
                const float a = acca[mi][nj][j] + b1[c];
                const float g = accg[mi][nj][j] + b1[2048 + c];
                const float ge = 0.5f * g * (1.f + erff(g * 0.70710678118654752f));
                ag[(size_t)r * 2048 + c] = f2b(a * ge);
            }
        }
}

// ---------------- attention: 2-way split-K (r14-exact) ----------------------
__global__ __launch_bounds__(256) void k_mattn(
    const u16* __restrict__ q, const u16* __restrict__ kbuf,
    const u16* __restrict__ vT, const float* __restrict__ tab,
    u16* __restrict__ ao, const int rowbase)
{
    __shared__ float mrg[2][64][37];
    const int bid = blockIdx.x, tid = threadIdx.x;
    const int h = bid & 7, qi = bid >> 3;
    const int qbase = qi << 6;
    const int w = tid >> 6, l = tid & 63;
    const int p = w >> 1, ko = (w & 1) << 9;            // key offset 0 / 512
    const int lr = l & 15, hi = l >> 4;
    const int qrA = qbase + p * 32 + lr;
    const int qrB = qrA + 16;
    const int b = (rowbase + qbase) >> 12;              // batch
    const bf16x8 qfA0 = *(const bf16x8*)&q[(size_t)qrA * 512 + h * 64 + hi * 8];
    const bf16x8 qfA1 = *(const bf16x8*)&q[(size_t)qrA * 512 + h * 64 + hi * 8 + 32];
    const bf16x8 qfB0 = *(const bf16x8*)&q[(size_t)qrB * 512 + h * 64 + hi * 8];
    const bf16x8 qfB1 = *(const bf16x8*)&q[(size_t)qrB * 512 + h * 64 + hi * 8 + 32];
    const u16* Kp = kbuf + (size_t)b * 524288 + h * 64;
    const u16* Vp = vT + ((size_t)(b * 8 + h)) * 65536;
    const int g2 = (hi & 1) * 2;
    const int srcA = lr + (g2 << 4);
    const int srcB = srcA + 16;
    const bool up = (hi >> 1) != 0;
    f32x4 accA[4], accB[4];
#pragma unroll
    for (int dj = 0; dj < 4; dj++)
#pragma unroll
        for (int e = 0; e < 4; e++) { accA[dj][e] = 0.f; accB[dj][e] = 0.f; }
    float mA = -1e30f, lA = 0.f, mB = -1e30f, lB = 0.f;
    for (int kk = 0; kk < 512; kk += 64) {
        const int kc = ko + kk;
        f32x4 stA[4], stB[4];
#pragma unroll
        for (int t = 0; t < 4; t++) {
            const size_t krow = (size_t)(kc + t * 16 + lr) * 512 + hi * 8;
            const bf16x8 kf0 = *(const bf16x8*)&Kp[krow];
            const bf16x8 kf1 = *(const bf16x8*)&Kp[krow + 32];
#pragma unroll
            for (int e = 0; e < 4; e++) { stA[t][e] = 0.f; stB[t][e] = 0.f; }
            stA[t] = mfma32(kf0, qfA0, stA[t]);
            stA[t] = mfma32(kf1, qfA1, stA[t]);
            stB[t] = mfma32(kf0, qfB0, stB[t]);
            stB[t] = mfma32(kf1, qfB1, stB[t]);
        }
        // hoist V fragments: loads overlap the softmax chains below
        bf16x8 vf[4][2];
#pragma unroll
        for (int dj = 0; dj < 4; dj++)
#pragma unroll
            for (int ks = 0; ks < 2; ks++)
                vf[dj][ks] = *(const bf16x8*)
                    &Vp[(size_t)(dj * 16 + lr) * 1024 + kc + ks * 32 + hi * 8];
        // ---- softmax group A ----
        bf16x8 pfragA[2], pfragB[2];
        {
            float mx = -1e30f;
#pragma unroll
            for (int t = 0; t < 4; t++)
#pragma unroll
                for (int j = 0; j < 4; j++) mx = fmaxf(mx, stA[t][j]);
            mx = fmaxf(mx, __shfl_xor(mx, 16));
            mx = fmaxf(mx, __shfl_xor(mx, 32));
            if (!__all(mx - mA <= 8.f)) {
                const float mnew = fmaxf(mA, mx);
                const float alpha = __expf(mA - mnew);
                lA *= alpha;
#pragma unroll
                for (int dj = 0; dj < 4; dj++)
#pragma unroll
                    for (int e = 0; e < 4; e++) accA[dj][e] *= alpha;
                mA = mnew;
            }
            float ps = 0.f;
            unsigned P64[4][2];
#pragma unroll
            for (int t = 0; t < 4; t++) {
                const float p0 = __expf(stA[t][0] - mA);
                const float p1 = __expf(stA[t][1] - mA);
                const float p2 = __expf(stA[t][2] - mA);
                const float p3 = __expf(stA[t][3] - mA);
                ps += (p0 + p1) + (p2 + p3);
                P64[t][0] = cvtpk(p0, p1);
                P64[t][1] = cvtpk(p2, p3);
            }
            ps += __shfl_xor(ps, 16);
            ps += __shfl_xor(ps, 32);
            lA += ps;
#pragma unroll
            for (int ks = 0; ks < 2; ks++) {
                const unsigned c0x = P64[ks * 2 + 0][0], c0y = P64[ks * 2 + 0][1];
                const unsigned c1x = P64[ks * 2 + 1][0], c1y = P64[ks * 2 + 1][1];
                const unsigned a0x = (unsigned)__shfl((int)c0x, srcA);
                const unsigned a0y = (unsigned)__shfl((int)c0y, srcA);
                const unsigned a1x = (unsigned)__shfl((int)c1x, srcA);
                const unsigned a1y = (unsigned)__shfl((int)c1y, srcA);
                const unsigned b0x = (unsigned)__shfl((int)c0x, srcB);
                const unsigned b0y = (unsigned)__shfl((int)c0y, srcB);
                const unsigned b1x = (unsigned)__shfl((int)c1x, srcB);
                const unsigned b1y = (unsigned)__shfl((int)c1y, srcB);
                union { unsigned u[4]; bf16x8 v; } pk;
                pk.u[0] = up ? a1x : a0x;
                pk.u[1] = up ? a1y : a0y;
                pk.u[2] = up ? b1x : b0x;
                pk.u[3] = up ? b1y : b0y;
                pfragA[ks] = pk.v;
            }
        }
        // ---- softmax group B ----
        {
            float mx = -1e30f;
#pragma unroll
            for (int t = 0; t < 4; t++)
#pragma unroll
                for (int j = 0; j < 4; j++) mx = fmaxf(mx, stB[t][j]);
            mx = fmaxf(mx, __shfl_xor(mx, 16));
            mx = fmaxf(mx, __shfl_xor(mx, 32));
            if (!__all(mx - mB <= 8.f)) {
                const float mnew = fmaxf(mB, mx);
                const float alpha = __expf(mB - mnew);
                lB *= alpha;
#pragma unroll
                for (int dj = 0; dj < 4; dj++)
#pragma unroll
                    for (int e = 0; e < 4; e++) accB[dj][e] *= alpha;
                mB = mnew;
            }
            float ps = 0.f;
            unsigned P64[4][2];
#pragma unroll
            for (int t = 0; t < 4; t++) {
                const float p0 = __expf(stB[t][0] - mB);
                const float p1 = __expf(stB[t][1] - mB);
                const float p2 = __expf(stB[t][2] - mB);
                const float p3 = __expf(stB[t][3] - mB);
                ps += (p0 + p1) + (p2 + p3);
                P64[t][0] = cvtpk(p0, p1);
                P64[t][1] = cvtpk(p2, p3);
            }
            ps += __shfl_xor(ps, 16);
            ps += __shfl_xor(ps, 32);
            lB += ps;
#pragma unroll
            for (int ks = 0; ks < 2; ks++) {
                const unsigned c0x = P64[ks * 2 + 0][0], c0y = P64[ks * 2 + 0][1];
                const unsigned c1x = P64[ks * 2 + 1][0], c1y = P64[ks * 2 + 1][1];
                const unsigned a0x = (unsigned)__shfl((int)c0x, srcA);
                const unsigned a0y = (unsigned)__shfl((int)c0y, srcA);
                const unsigned a1x = (unsigned)__shfl((int)c1x, srcA);
                const unsigned a1y = (unsigned)__shfl((int)c1y, srcA);
                const unsigned b0x = (unsigned)__shfl((int)c0x, srcB);
                const unsigned b0y = (unsigned)__shfl((int)c0y, srcB);
                const unsigned b1x = (unsigned)__shfl((int)c1x, srcB);
                const unsigned b1y = (unsigned)__shfl((int)c1y, srcB);
                union { unsigned u[4]; bf16x8 v; } pk;
                pk.u[0] = up ? a1x : a0x;
                pk.u[1] = up ? a1y : a0y;
                pk.u[2] = up ? b1x : b0x;
                pk.u[3] = up ? b1y : b0y;
                pfragB[ks] = pk.v;
            }
        }
        // ---- PV ----
#pragma unroll
        for (int dj = 0; dj < 4; dj++)
#pragma unroll
            for (int ks = 0; ks < 2; ks++) {
                accA[dj] = mfma32(vf[dj][ks], pfragA[ks], accA[dj]);
                accB[dj] = mfma32(vf[dj][ks], pfragB[ks], accB[dj]);
            }
    }
    // ---- split-K merge: odd wave publishes, even wave merges + writes ------
    if (w & 1) {
        float* dst = mrg[p][l];
        dst[0] = mA; dst[1] = lA; dst[2] = mB; dst[3] = lB;
#pragma unroll
        for (int dj = 0; dj < 4; dj++)
#pragma unroll
            for (int e = 0; e < 4; e++) {
                dst[4 + dj * 4 + e]  = accA[dj][e];
                dst[20 + dj * 4 + e] = accB[dj][e];
            }
    }
    __syncthreads();
    if (w & 1) return;
    {
        const float* src = mrg[p][l];
        const float m1A = src[0], l1A = src[1], m1B = src[2], l1B = src[3];
        {
            const float mm = fmaxf(mA, m1A);
            const float f0 = __expf(mA - mm), f1 = __expf(m1A - mm);
            lA = lA * f0 + l1A * f1;
#pragma unroll
            for (int dj = 0; dj < 4; dj++)
#pragma unroll
                for (int e = 0; e < 4; e++)
                    accA[dj][e] = accA[dj][e] * f0 + src[4 + dj * 4 + e] * f1;
        }
        {
            const float mm = fmaxf(mB, m1B);
            const float f0 = __expf(mB - mm), f1 = __expf(m1B - mm);
            lB = lB * f0 + l1B * f1;
#pragma unroll
            for (int dj = 0; dj < 4; dj++)
#pragma unroll
                for (int e = 0; e < 4; e++)
                    accB[dj][e] = accB[dj][e] * f0 + src[20 + dj * 4 + e] * f1;
        }
    }
    const float ivA = 1.f / lA, ivB = 1.f / lB;
#pragma unroll
    for (int g = 0; g < 2; g++) {
        const int qr = g ? qrB : qrA;
        const float invl = g ? ivB : ivA;
#pragma unroll
        for (int dj = 0; dj < 4; dj++) {
            const f32x4 a = g ? accB[dj] : accA[dj];
            const int d0 = dj * 16 + hi * 4;
            float y[4];
#pragma unroll
            for (int pp = 0; pp < 2; pp++) {
                const float x0 = a[2 * pp] * invl;
                const float x1 = a[2 * pp + 1] * invl;
                const int ii = (d0 >> 1) + pp;
                if (ii < 16) {
                    const float cc = tab[((size_t)qr << 5) + (ii << 1)];
                    const float ss = tab[((size_t)qr << 5) + (ii << 1) + 1];
                    y[2 * pp]     = fmaf(x0, cc, x1 * ss);    // inverse rotation
                    y[2 * pp + 1] = fmaf(x1, cc, -x0 * ss);
                } else {
                    y[2 * pp] = x0; y[2 * pp + 1] = x1;
                }
            }
            ushort4 o;
            o.x = f2b(y[0]); o.y = f2b(y[1]); o.z = f2b(y[2]); o.w = f2b(y[3]);
            *(ushort4*)&ao[(size_t)qr * 512 + h * 64 + d0] = o;
        }
    }
}

// ---------------- final: LN + dot with wproj (bf16 in, f32 out) -------------
__global__ __launch_bounds__(128) void k_final(
    const u16* __restrict__ dec, const float* __restrict__ w,
    const float* __restrict__ bb, const float* __restrict__ wproj,
    const float* __restrict__ bproj, float* __restrict__ out)
{
    const int r = blockIdx.x, tid = threadIdx.x, c0 = tid << 2;
    const ushort4 xi = *(const ushort4*)&dec[(size_t)r * 512 + c0];
    float4 x;
    x.x = b2f(xi.x); x.y = b2f(xi.y); x.z = b2f(xi.z); x.w = b2f(xi.w);
    float s  = x.x + x.y + x.z + x.w;
    float s2 = x.x * x.x + x.y * x.y + x.z * x.z + x.w * x.w;
#pragma unroll
    for (int o = 32; o > 0; o >>= 1) { s += __shfl_down(s, o); s2 += __shfl_down(s2, o); }
    __shared__ float buf[4];
    if ((tid & 63) == 0) { buf[(tid >> 6) << 1] = s; buf[((tid >> 6) << 1) + 1] = s2; }
    __syncthreads();
    s = buf[0] + buf[2]; s2 = buf[1] + buf[3];
    const float mu = s * (1.f / 512.f);
    const float rs = rsqrtf(s2 * (1.f / 512.f) - mu * mu + 1e-5f);
    const float4 w4 = *(const float4*)&w[c0];
    const float4 b4 = *(const float4*)&bb[c0];
    const float4 p4 = *(const float4*)&wproj[c0];
    float part = ((x.x - mu) * rs * w4.x + b4.x) * p4.x
               + ((x.y - mu) * rs * w4.y + b4.y) * p4.y
               + ((x.z - mu) * rs * w4.z + b4.z) * p4.z
               + ((x.w - mu) * rs * w4.w + b4.w) * p4.w;
#pragma unroll
    for (int o = 32; o > 0; o >>= 1) part += __shfl_down(part, o);
    __shared__ float buf2[2];
    if ((tid & 63) == 0) buf2[tid >> 6] = part;
    __syncthreads();
    if (tid == 0) out[r] = buf2[0] + buf2[1] + bproj[0];
}

// ---------------------------------------------------------------------------
extern "C" void kernel_launch(void* const* d_in, const int* in_sizes, int n_in,
                              void* d_out, int out_size, void* d_ws, size_t ws_size,
                              hipStream_t stream)
{
    (void)in_sizes; (void)n_in; (void)out_size;
    const float* enc  = (const float*)d_in[0];
    const float* lts  = (const float*)d_in[1];
    const int*   qidx = (const int*)  d_in[2];
    const float* qts  = (const float*)d_in[3];
    const float* uemb = (const float*)d_in[4];
    const float* vpb  = (const float*)d_in[6];
    const float* canw = (const float*)d_in[7];
    const float* canb = (const float*)d_in[8];
    const float* ccw  = (const float*)d_in[9];
    const float* ccb  = (const float*)d_in[10];
    const float* wq   = (const float*)d_in[11];
    const float* wkv  = (const float*)d_in[12];
    const float* wo   = (const float*)d_in[13];
    const float* bo   = (const float*)d_in[14];
    const float* flnw = (const float*)d_in[15];
    const float* flnb = (const float*)d_in[16];
    const float* w1   = (const float*)d_in[17];
    const float* b1   = (const float*)d_in[18];
    const float* w2   = (const float*)d_in[19];
    const float* b2   = (const float*)d_in[20];
    const float* olnw = (const float*)d_in[21];
    const float* olnb = (const float*)d_in[22];
    const float* wpj  = (const float*)d_in[23];
    const float* bpj  = (const float*)d_in[24];
    float* outp = (float*)d_out;

    // workspace: f32 tabs, then bf16 region
    float* tabq = (float*)d_ws;              // 16384*32
    float* tabl = tabq + 524288;             // 4096*32
    u16* wqb  = (u16*)(tabl + 131072);       // 512*512
    u16* wkvb = wqb + 262144;                // 1024*512
    u16* wob  = wkvb + 524288;               // 512*512
    u16* w1b  = wob + 262144;                // 4096*512
    u16* w2b  = w1b + 2097152;               // 512*2048
    u16* cn   = w2b + 1048576;               // 4096*512
    u16* kb   = cn + 2097152;                // 4096*512
    u16* vT   = kb + 2097152;                // 4*8*64*1024
    const size_t base_b = 2621440ull + 20971520ull;       // tabs + bf16 shared
    int CQ = 16384;
    while (CQ > 512 &&
           base_b + (size_t)CQ * 5120 + (size_t)(CQ < 4096 ? CQ : 4096) * 4096 > ws_size)
        CQ >>= 1;
    int SF = CQ;
    while (SF > 512 && base_b + (size_t)CQ * 5120 + (size_t)SF * 4096 > ws_size)
        SF >>= 1;
    u16* qtokC = vT + 2097152;               // CQ*512
    u16* xnC   = qtokC + (size_t)CQ * 512;   // CQ*512 (reused: ln_dec)
    u16* qC    = xnC + (size_t)CQ * 512;     // CQ*512 (reused: dec_final)
    u16* aoC   = qC + (size_t)CQ * 512;      // CQ*512
    u16* d2C   = aoC + (size_t)CQ * 512;     // CQ*512
    u16* agC   = d2C + (size_t)CQ * 512;     // SF*2048

    k_cvt<<<256, 256, 0, stream>>>(wq, wqb, 262144);
    k_cvt<<<512, 256, 0, stream>>>(wkv, wkvb, 524288);
    k_cvt<<<256, 256, 0, stream>>>(wo, wob, 262144);
    k_cvt<<<2048, 256, 0, stream>>>(w1, w1b, 2097152);
    k_cvt<<<1024, 256, 0, stream>>>(w2, w2b, 1048576);
    k_rope_tab16<<<1024, 256, 0, stream>>>(qts, tabq, 16384);
    k_rope_tab16<<<256, 256, 0, stream>>>(lts, tabl, 4096);
    k_ln_f<<<4096, 128, 0, stream>>>(enc, ccw, ccb, cn);
    k_mgemm<1><<<dim3(8, 32), 256, 0, stream>>>(cn, wkvb, 1024, 512,
                                                kb, vT, nullptr, nullptr, tabl);

    for (int g0 = 0; g0 < 16384; g0 += CQ) {
        const float* tabc = tabq + (size_t)g0 * 32;
        k_qtok_ln<<<CQ, 128, 0, stream>>>(qidx + g0, uemb, vpb, canw, canb,
                                          qtokC, xnC);
        k_mgemm<0><<<dim3(4, CQ / 128), 256, 0, stream>>>(xnC, wqb, 512, 512,
                                                          qC, nullptr, nullptr, nullptr, tabc);
        k_mattn<<<(CQ / 64) * 8, 256, 0, stream>>>(qC, kb, vT, tabc, aoC, g0);
        k_mgemm<2><<<dim3(4, CQ / 128), 256, 0, stream>>>(aoC, wob, 512, 512,
                                                          d2C, nullptr, bo, qtokC, nullptr);
        k_ln_h<<<CQ, 128, 0, stream>>>(d2C, flnw, flnb, xnC);
        for (int f0 = 0; f0 < CQ; f0 += SF) {
            k_mffn1<<<dim3(32, SF / 128), 256, 0, stream>>>(xnC + (size_t)f0 * 512,
                                                            w1b, b1, agC);
            k_mgemm<2><<<dim3(4, SF / 128), 256, 0, stream>>>(agC, w2b, 512, 2048,
                                                              qC + (size_t)f0 * 512, nullptr,
                                                              b2, d2C + (size_t)f0 * 512, nullptr);
            k_final<<<SF, 128, 0, stream>>>(qC + (size_t)f0 * 512, olnw, olnb,
                                            wpj, bpj, outp + g0 + f0);
        }
    }
}